// Round 1
// baseline (12244.663 us; speedup 1.0000x reference)
//
#include <hip/hip_runtime.h>
#include <stdint.h>
#include <math.h>

// ---------------------------------------------------------------------------
// GatedMultiplicativeSelfAttention: B=8, S=2048, D=512, H=512
// Pipeline:
//  1) rin[:, :512] = bf16(x)
//  2) xT = bf16(x^T) per batch
//  3) Wx = x @ W^T                    (bf16 MFMA GEMM)
//  4) per batch: s = Wx @ x^T ; softmax(mask diag) in-place (bf16) ; c = a @ x
//     c written into rin[:, 512:1024]
//  5) ring = rin * sigmoid(rin @ Wg^T)
//  6) xw_f/xw_b = ring @ Wih^T + bih  (bf16)
//  7) persistent bidirectional GRU scan (64 WGs, per-direction barrier)
//  8) out = x + hcat @ Wp^T + bp
// ---------------------------------------------------------------------------

typedef __attribute__((ext_vector_type(8))) short bfx8;
typedef __attribute__((ext_vector_type(4))) float fx4;

__device__ __forceinline__ float bf2f(unsigned short u) {
  union { unsigned int i; float f; } v; v.i = ((unsigned int)u) << 16; return v.f;
}
__device__ __forceinline__ unsigned short f2bf(float f) {
  union { float f; unsigned int i; } v; v.f = f;
  unsigned int x = v.i;
  return (unsigned short)((x + 0x7fffu + ((x >> 16) & 1u)) >> 16);
}

// ---------------- generic BT GEMM: C[M,N] = A[M,K] * B[N,K]^T ---------------
#define EP_BF16 0
#define EP_F32 1
#define EP_GATE 2
#define EP_RESID 3
#define EP_BIASBF 4

template <int EP>
__global__ __launch_bounds__(256)
void gemm_bt(const unsigned short* __restrict__ A, int lda,
             const unsigned short* __restrict__ B, int ldb,
             void* __restrict__ Cp, int ldc, int K,
             const void* __restrict__ P, const float* __restrict__ bias) {
  __shared__ __attribute__((aligned(16))) unsigned short As[128 * 64];
  __shared__ __attribute__((aligned(16))) unsigned short Bs[128 * 64];
  const int tid = threadIdx.x;
  const int w = tid >> 6, l = tid & 63;
  const int bm = blockIdx.y << 7, bn = blockIdx.x << 7;
  const int wm = (w >> 1) << 6, wn = (w & 1) << 6;
  const int fr = l & 15, fk = (l >> 4) << 3;
  fx4 zero4 = {0.f, 0.f, 0.f, 0.f};
  fx4 acc[4][4];
#pragma unroll
  for (int i = 0; i < 4; ++i)
#pragma unroll
    for (int j = 0; j < 4; ++j) acc[i][j] = zero4;

  for (int k0 = 0; k0 < K; k0 += 64) {
#pragma unroll
    for (int c = 0; c < 4; ++c) {
      int e = (tid + (c << 8)) << 3;
      int r = e >> 6, cc = e & 63;
      *(uint4*)&As[e] = *(const uint4*)&A[(size_t)(bm + r) * lda + k0 + cc];
      *(uint4*)&Bs[e] = *(const uint4*)&B[(size_t)(bn + r) * ldb + k0 + cc];
    }
    __syncthreads();
#pragma unroll
    for (int kk = 0; kk < 64; kk += 32) {
      bfx8 a[4], b[4];
#pragma unroll
      for (int m = 0; m < 4; ++m) a[m] = *(const bfx8*)&As[(wm + (m << 4) + fr) * 64 + kk + fk];
#pragma unroll
      for (int n = 0; n < 4; ++n) b[n] = *(const bfx8*)&Bs[(wn + (n << 4) + fr) * 64 + kk + fk];
#pragma unroll
      for (int m = 0; m < 4; ++m)
#pragma unroll
        for (int n = 0; n < 4; ++n)
          acc[m][n] = __builtin_amdgcn_mfma_f32_16x16x32_bf16(a[m], b[n], acc[m][n], 0, 0, 0);
    }
    __syncthreads();
  }
  const int er = (l >> 4) << 2, ec = l & 15;
#pragma unroll
  for (int m = 0; m < 4; ++m)
#pragma unroll
    for (int n = 0; n < 4; ++n)
#pragma unroll
      for (int i = 0; i < 4; ++i) {
        int gr = bm + wm + (m << 4) + er + i;
        int gc = bn + wn + (n << 4) + ec;
        float v = acc[m][n][i];
        size_t idx = (size_t)gr * ldc + gc;
        if constexpr (EP == EP_F32) {
          ((float*)Cp)[idx] = v;
        } else if constexpr (EP == EP_BF16) {
          ((unsigned short*)Cp)[idx] = f2bf(v);
        } else if constexpr (EP == EP_BIASBF) {
          ((unsigned short*)Cp)[idx] = f2bf(v + bias[gc]);
        } else if constexpr (EP == EP_GATE) {
          float rv = bf2f(((const unsigned short*)P)[idx]);
          float sg = 1.f / (1.f + __expf(-v));
          ((unsigned short*)Cp)[idx] = f2bf(rv * sg);
        } else {  // EP_RESID
          float xv = ((const float*)P)[idx];
          ((float*)Cp)[idx] = v + xv + bias[gc];
        }
      }
}

// ---------------- small prep kernels ----------------------------------------
__global__ __launch_bounds__(256)
void cast_w_kernel(const float* __restrict__ in, unsigned short* __restrict__ out, int n) {
  int e = (blockIdx.x * 256 + threadIdx.x) * 4;
  if (e >= n) return;
  float4 v = *(const float4*)&in[e];
  ushort4 u;
  u.x = f2bf(v.x); u.y = f2bf(v.y); u.z = f2bf(v.z); u.w = f2bf(v.w);
  *(ushort4*)&out[e] = u;
}

// x f32 [16384,512] -> rin bf16 left half (pitch 1024)
__global__ __launch_bounds__(256)
void cast_x_kernel(const float* __restrict__ x, unsigned short* __restrict__ rin) {
  int idx = blockIdx.x * 256 + threadIdx.x;
  int e = idx * 4;
  float4 v = *(const float4*)&x[e];
  ushort4 u;
  u.x = f2bf(v.x); u.y = f2bf(v.y); u.z = f2bf(v.z); u.w = f2bf(v.w);
  int row = e >> 9, col = e & 511;
  *(ushort4*)&rin[(size_t)row * 1024 + col] = u;
}

// per-batch transpose: xT[b][d][j] = bf16(x[b][j][d])
__global__ __launch_bounds__(256)
void transpose_kernel(const float* __restrict__ x, unsigned short* __restrict__ xT) {
  __shared__ unsigned short tile[64][65];
  const int b = blockIdx.z;
  const int j0 = blockIdx.x << 6, d0 = blockIdx.y << 6;
  const int tx = threadIdx.x & 63, ty = threadIdx.x >> 6;
  const float* xb = x + (size_t)b * 2048 * 512;
  unsigned short* xTb = xT + (size_t)b * 512 * 2048;
#pragma unroll
  for (int rep = 0; rep < 16; ++rep) {
    int jj = (rep << 2) + ty;
    tile[jj][tx] = f2bf(xb[(size_t)(j0 + jj) * 512 + d0 + tx]);
  }
  __syncthreads();
#pragma unroll
  for (int rep = 0; rep < 16; ++rep) {
    int dd = (rep << 2) + ty;
    xTb[(size_t)(d0 + dd) * 2048 + j0 + tx] = tile[tx][dd];
  }
}

// row softmax with masked diagonal, f32 in -> bf16 out in place (row pitch 4096 ushorts)
__global__ __launch_bounds__(256)
void softmax_kernel(float* __restrict__ sbase) {
  __shared__ float red[8];
  const int i = blockIdx.x;
  float* sp = sbase + (size_t)i * 2048;
  const int tid = threadIdx.x;
  const int j0 = tid << 3;
  float4 va = *(const float4*)&sp[j0];
  float4 vb = *(const float4*)&sp[j0 + 4];
  float v[8] = {va.x, va.y, va.z, va.w, vb.x, vb.y, vb.z, vb.w};
#pragma unroll
  for (int k = 0; k < 8; ++k)
    if (j0 + k == i) v[k] = -1e30f;
  float m = v[0];
#pragma unroll
  for (int k = 1; k < 8; ++k) m = fmaxf(m, v[k]);
#pragma unroll
  for (int off = 32; off > 0; off >>= 1) m = fmaxf(m, __shfl_down(m, off, 64));
  if ((tid & 63) == 0) red[tid >> 6] = m;
  __syncthreads();
  m = fmaxf(fmaxf(red[0], red[1]), fmaxf(red[2], red[3]));
  float s = 0.f;
#pragma unroll
  for (int k = 0; k < 8; ++k) {
    float e = __expf(v[k] - m);
    if (j0 + k == i) e = 0.f;
    v[k] = e;
    s += e;
  }
#pragma unroll
  for (int off = 32; off > 0; off >>= 1) s += __shfl_down(s, off, 64);
  if ((tid & 63) == 0) red[4 + (tid >> 6)] = s;
  __syncthreads();  // also guarantees every wave finished its loads (in-place safety)
  s = red[4] + red[5] + red[6] + red[7];
  float inv = 1.f / s;
  unsigned int pk[4];
#pragma unroll
  for (int k = 0; k < 4; ++k) {
    unsigned int lo = f2bf(v[2 * k] * inv);
    unsigned int hi = f2bf(v[2 * k + 1] * inv);
    pk[k] = lo | (hi << 16);
  }
  uint4 o; o.x = pk[0]; o.y = pk[1]; o.z = pk[2]; o.w = pk[3];
  *(uint4*)&((unsigned short*)sp)[j0] = o;
}

// ---------------- persistent bidirectional GRU ------------------------------
// 64 WGs: dir = wg>>5 (0 fwd, 1 bwd), slice = wg&31 owns 16 hidden units.
// Whh rows (r,z,n for those units) pre-loaded as MFMA B-fragments in registers.
// h state: bf16, double-buffered in global, device-scope barrier per step.
__global__ __launch_bounds__(256)
void gru_kernel(const unsigned short* __restrict__ xw_f,
                const unsigned short* __restrict__ xw_b,
                const unsigned short* __restrict__ Whh_f,
                const unsigned short* __restrict__ Whh_b,
                const float* __restrict__ bhh_f,
                const float* __restrict__ bhh_b,
                unsigned short* __restrict__ hcat,
                unsigned short* __restrict__ hstate,  // [2 dir][2 phase][8][512]
                int* __restrict__ ctr) {              // [2] padded
  const int wg = blockIdx.x;
  const int dir = wg >> 5;
  const int slice = wg & 31;
  const int u0 = slice << 4;
  const unsigned short* __restrict__ xwp = dir ? xw_b : xw_f;
  const unsigned short* __restrict__ Whh = dir ? Whh_b : Whh_f;
  const float* __restrict__ bhh = dir ? bhh_b : bhh_f;
  unsigned short* hbase = hstate + (size_t)dir * 2 * 4096;
  int* myctr = ctr + dir * 32;

  __shared__ __attribute__((aligned(16))) unsigned short hbf[16 * 544];
  __shared__ float ghbuf[3 * 128];

  const int tid = threadIdx.x;
  const int w = tid >> 6, l = tid & 63;
  const int fr = l & 15, fk = (l >> 4) << 3;

  for (int i = tid; i < 16 * 544; i += 256) hbf[i] = 0;

  bfx8 wfrag[16];
  if (w < 3) {
    const int grow = (w << 9) + u0 + fr;  // gate*512 + unit
#pragma unroll
    for (int ks = 0; ks < 16; ++ks)
      wfrag[ks] = *(const bfx8*)&Whh[(size_t)grow * 512 + (ks << 5) + fk];
  }
  const int b_ = tid >> 4, uu_ = tid & 15;
  float bh0 = 0.f, bh1 = 0.f, bh2 = 0.f;
  if (tid < 128) {
    bh0 = bhh[u0 + uu_];
    bh1 = bhh[512 + u0 + uu_];
    bh2 = bhh[1024 + u0 + uu_];
  }
  __syncthreads();

  float xr = 0.f, xz = 0.f, xn = 0.f;
  if (tid < 128) {
    int ta = dir ? 2047 : 0;
    size_t rb = (size_t)(b_ * 2048 + ta) * 1536;
    xr = bf2f(xwp[rb + u0 + uu_]);
    xz = bf2f(xwp[rb + 512 + u0 + uu_]);
    xn = bf2f(xwp[rb + 1024 + u0 + uu_]);
  }

  for (int t = 0; t < 2048; ++t) {
    const int t_act = dir ? (2047 - t) : t;
    {  // load h_t (phase t&1) into hbf rows 0..7 (L1-bypass loads)
      const unsigned short* hr = hbase + (size_t)(t & 1) * 4096;
      int off = tid << 4;
      int hb = off >> 9, hc = off & 511;
      const volatile unsigned int* src = (const volatile unsigned int*)(hr + off);
      unsigned int* dst = (unsigned int*)&hbf[hb * 544 + hc];
      unsigned int d0 = src[0], d1 = src[1], d2 = src[2], d3 = src[3];
      unsigned int d4 = src[4], d5 = src[5], d6 = src[6], d7 = src[7];
      dst[0] = d0; dst[1] = d1; dst[2] = d2; dst[3] = d3;
      dst[4] = d4; dst[5] = d5; dst[6] = d6; dst[7] = d7;
    }
    __syncthreads();
    if (w < 3) {
      fx4 z4 = {0.f, 0.f, 0.f, 0.f};
      fx4 acc0 = z4, acc1 = z4;
#pragma unroll
      for (int ks = 0; ks < 16; ks += 2) {
        bfx8 a0 = *(const bfx8*)&hbf[fr * 544 + (ks << 5) + fk];
        bfx8 a1 = *(const bfx8*)&hbf[fr * 544 + ((ks + 1) << 5) + fk];
        acc0 = __builtin_amdgcn_mfma_f32_16x16x32_bf16(a0, wfrag[ks], acc0, 0, 0, 0);
        acc1 = __builtin_amdgcn_mfma_f32_16x16x32_bf16(a1, wfrag[ks + 1], acc1, 0, 0, 0);
      }
      if (l < 32) {
#pragma unroll
        for (int i = 0; i < 4; ++i) {
          int bb = ((l >> 4) << 2) + i;  // batch row 0..7
          ghbuf[(w << 7) + (bb << 4) + fr] = acc0[i] + acc1[i];
        }
      }
    }
    __syncthreads();
    float nxr = 0.f, nxz = 0.f, nxn = 0.f;  // prefetch next xw before the barrier
    if (t + 1 < 2048 && tid < 128) {
      int ta = dir ? (2046 - t) : (t + 1);
      size_t rb = (size_t)(b_ * 2048 + ta) * 1536;
      nxr = bf2f(xwp[rb + u0 + uu_]);
      nxz = bf2f(xwp[rb + 512 + u0 + uu_]);
      nxn = bf2f(xwp[rb + 1024 + u0 + uu_]);
    }
    if (tid < 128) {
      float ghr = ghbuf[tid] + bh0;
      float ghz = ghbuf[128 + tid] + bh1;
      float ghn = ghbuf[256 + tid] + bh2;
      float r = 1.f / (1.f + __expf(-(xr + ghr)));
      float z = 1.f / (1.f + __expf(-(xz + ghz)));
      float n = tanhf(xn + r * ghn);
      float hprev = bf2f(hbf[b_ * 544 + u0 + uu_]);
      float hn = (1.f - z) * n + z * hprev;
      unsigned short hnb = f2bf(hn);
      unsigned short* hw = hbase + (size_t)((t + 1) & 1) * 4096;
      hw[(b_ << 9) + u0 + uu_] = hnb;
      hcat[((size_t)(b_ * 2048 + t_act) << 10) + (dir << 9) + u0 + uu_] = hnb;
    }
    xr = nxr; xz = nxz; xn = nxn;
    if (t + 1 < 2048) {
      __syncthreads();  // drains all waves' stores to L2
      if (tid == 0) {
        __hip_atomic_fetch_add(myctr, 1, __ATOMIC_RELEASE, __HIP_MEMORY_SCOPE_AGENT);
        const int target = (t + 1) << 5;
        while (__hip_atomic_load(myctr, __ATOMIC_RELAXED, __HIP_MEMORY_SCOPE_AGENT) < target)
          __builtin_amdgcn_s_sleep(1);
        __threadfence();  // acquire: invalidate stale cached h
      }
      __syncthreads();
    }
  }
}

// ---------------------------------------------------------------------------
extern "C" void kernel_launch(void* const* d_in, const int* in_sizes, int n_in,
                              void* d_out, int out_size, void* d_ws, size_t ws_size,
                              hipStream_t stream) {
  (void)in_sizes; (void)n_in; (void)out_size;
  const float* x    = (const float*)d_in[0];
  const float* W    = (const float*)d_in[1];
  const float* Wg   = (const float*)d_in[2];
  const float* Wihf = (const float*)d_in[3];
  const float* Whhf = (const float*)d_in[4];
  const float* bihf = (const float*)d_in[5];
  const float* bhhf = (const float*)d_in[6];
  const float* Wihb = (const float*)d_in[7];
  const float* Whhb = (const float*)d_in[8];
  const float* bihb = (const float*)d_in[9];
  const float* bhhb = (const float*)d_in[10];
  const float* Wp   = (const float*)d_in[11];
  const float* bp   = (const float*)d_in[12];
  float* out = (float*)d_out;

  char* base = (char*)d_ws;
  size_t off = 0;
  auto alloc = [&](size_t b) { void* r = base + off; off += (b + 255) & ~(size_t)255; return r; };
  unsigned short* xT   = (unsigned short*)alloc(8ull * 512 * 2048 * 2);
  unsigned short* xwf  = (unsigned short*)alloc(16384ull * 1536 * 2);
  unsigned short* xwb  = (unsigned short*)alloc(16384ull * 1536 * 2);
  unsigned short* rin  = (unsigned short*)alloc(16384ull * 1024 * 2);
  unsigned short* ring = (unsigned short*)alloc(16384ull * 1024 * 2);
  unsigned short* wW   = (unsigned short*)alloc(512ull * 512 * 2);
  unsigned short* wWg  = (unsigned short*)alloc(1024ull * 1024 * 2);
  unsigned short* wIf  = (unsigned short*)alloc(1536ull * 1024 * 2);
  unsigned short* wHf  = (unsigned short*)alloc(1536ull * 512 * 2);
  unsigned short* wIb  = (unsigned short*)alloc(1536ull * 1024 * 2);
  unsigned short* wHb  = (unsigned short*)alloc(1536ull * 512 * 2);
  unsigned short* wP   = (unsigned short*)alloc(512ull * 1024 * 2);
  unsigned short* hst  = (unsigned short*)alloc(2ull * 2 * 4096 * 2);
  int* ctr             = (int*)alloc(256);
  // overlays (lifetimes disjoint):
  float* sbuf = (float*)xwf;           // s scores, dead before xw_f written
  unsigned short* wxbf = ring;         // Wx, dead before ring written
  unsigned short* hcat = rin;          // GRU output, written after rin dead
  if (off > ws_size) return;           // fail loudly (output stays poisoned)

  hipMemsetAsync(hst, 0, 2 * 2 * 4096 * 2, stream);
  hipMemsetAsync(ctr, 0, 256, stream);

  // weight casts
  cast_w_kernel<<<256,  256, 0, stream>>>(W,    wW,  512 * 512);
  cast_w_kernel<<<1024, 256, 0, stream>>>(Wg,   wWg, 1024 * 1024);
  cast_w_kernel<<<1536, 256, 0, stream>>>(Wihf, wIf, 1536 * 1024);
  cast_w_kernel<<<768,  256, 0, stream>>>(Whhf, wHf, 1536 * 512);
  cast_w_kernel<<<1536, 256, 0, stream>>>(Wihb, wIb, 1536 * 1024);
  cast_w_kernel<<<768,  256, 0, stream>>>(Whhb, wHb, 1536 * 512);
  cast_w_kernel<<<512,  256, 0, stream>>>(Wp,   wP,  512 * 1024);

  cast_x_kernel<<<8192, 256, 0, stream>>>(x, rin);
  transpose_kernel<<<dim3(32, 8, 8), 256, 0, stream>>>(x, xT);

  // Wx = x @ W^T  (A = rin left half)
  gemm_bt<EP_BF16><<<dim3(4, 128), 256, 0, stream>>>(rin, 1024, wW, 512, wxbf, 512, 512, nullptr, nullptr);

  // attention per batch: s -> softmax -> c (into rin[:,512:])
  for (int b = 0; b < 8; ++b) {
    gemm_bt<EP_F32><<<dim3(16, 16), 256, 0, stream>>>(
        wxbf + (size_t)b * 2048 * 512, 512, rin + (size_t)b * 2048 * 1024, 1024,
        sbuf, 2048, 512, nullptr, nullptr);
    softmax_kernel<<<2048, 256, 0, stream>>>(sbuf);
    gemm_bt<EP_BF16><<<dim3(4, 16), 256, 0, stream>>>(
        (const unsigned short*)sbuf, 4096, xT + (size_t)b * 512 * 2048, 2048,
        rin + (size_t)b * 2048 * 1024 + 512, 1024, 2048, nullptr, nullptr);
  }

  // gated concat: ring = rin * sigmoid(rin @ Wg^T)
  gemm_bt<EP_GATE><<<dim3(8, 128), 256, 0, stream>>>(rin, 1024, wWg, 1024, ring, 1024, 1024, rin, nullptr);

  // GRU input gates
  gemm_bt<EP_BIASBF><<<dim3(12, 128), 256, 0, stream>>>(ring, 1024, wIf, 1024, xwf, 1536, 1024, nullptr, bihf);
  gemm_bt<EP_BIASBF><<<dim3(12, 128), 256, 0, stream>>>(ring, 1024, wIb, 1024, xwb, 1536, 1024, nullptr, bihb);

  // persistent bidirectional GRU scan (writes hcat over rin region)
  gru_kernel<<<64, 256, 0, stream>>>(xwf, xwb, wHf, wHb, bhhf, bhhb, hcat, hst, ctr);

  // out = x + hcat @ Wp^T + bp
  gemm_bt<EP_RESID><<<dim3(4, 128), 256, 0, stream>>>(hcat, 1024, wP, 1024, out, 512, 1024, x, bp);
}

// Round 2
// 7044.415 us; speedup vs baseline: 1.7382x; 1.7382x over previous
//
#include <hip/hip_runtime.h>
#include <stdint.h>
#include <math.h>

// ---------------------------------------------------------------------------
// GatedMultiplicativeSelfAttention: B=8, S=2048, D=512, H=512
// Pipeline:
//  1) rin[:, :512] = bf16(x)
//  2) xT = bf16(x^T) per batch
//  3) Wx = x @ W^T                    (bf16 MFMA GEMM)
//  4) per batch: s = Wx @ x^T ; softmax(mask diag) in-place (bf16) ; c = a @ x
//     c written into rin[:, 512:1024]
//  5) ring = rin * sigmoid(rin @ Wg^T)
//  6) xw_f/xw_b = ring @ Wih^T + bih  (bf16)
//  7) persistent bidirectional GRU scan (64 WGs, fence-free flag protocol)
//  8) out = x + hcat @ Wp^T + bp
// ---------------------------------------------------------------------------

typedef __attribute__((ext_vector_type(8))) short bfx8;
typedef __attribute__((ext_vector_type(4))) float fx4;

__device__ __forceinline__ float bf2f(unsigned short u) {
  union { unsigned int i; float f; } v; v.i = ((unsigned int)u) << 16; return v.f;
}
__device__ __forceinline__ unsigned short f2bf(float f) {
  union { float f; unsigned int i; } v; v.f = f;
  unsigned int x = v.i;
  return (unsigned short)((x + 0x7fffu + ((x >> 16) & 1u)) >> 16);
}

// ---------------- generic BT GEMM: C[M,N] = A[M,K] * B[N,K]^T ---------------
#define EP_BF16 0
#define EP_F32 1
#define EP_GATE 2
#define EP_RESID 3
#define EP_BIASBF 4

template <int EP>
__global__ __launch_bounds__(256)
void gemm_bt(const unsigned short* __restrict__ A, int lda,
             const unsigned short* __restrict__ B, int ldb,
             void* __restrict__ Cp, int ldc, int K,
             const void* __restrict__ P, const float* __restrict__ bias) {
  __shared__ __attribute__((aligned(16))) unsigned short As[128 * 64];
  __shared__ __attribute__((aligned(16))) unsigned short Bs[128 * 64];
  const int tid = threadIdx.x;
  const int w = tid >> 6, l = tid & 63;
  const int bm = blockIdx.y << 7, bn = blockIdx.x << 7;
  const int wm = (w >> 1) << 6, wn = (w & 1) << 6;
  const int fr = l & 15, fk = (l >> 4) << 3;
  fx4 zero4 = {0.f, 0.f, 0.f, 0.f};
  fx4 acc[4][4];
#pragma unroll
  for (int i = 0; i < 4; ++i)
#pragma unroll
    for (int j = 0; j < 4; ++j) acc[i][j] = zero4;

  for (int k0 = 0; k0 < K; k0 += 64) {
#pragma unroll
    for (int c = 0; c < 4; ++c) {
      int e = (tid + (c << 8)) << 3;
      int r = e >> 6, cc = e & 63;
      *(uint4*)&As[e] = *(const uint4*)&A[(size_t)(bm + r) * lda + k0 + cc];
      *(uint4*)&Bs[e] = *(const uint4*)&B[(size_t)(bn + r) * ldb + k0 + cc];
    }
    __syncthreads();
#pragma unroll
    for (int kk = 0; kk < 64; kk += 32) {
      bfx8 a[4], b[4];
#pragma unroll
      for (int m = 0; m < 4; ++m) a[m] = *(const bfx8*)&As[(wm + (m << 4) + fr) * 64 + kk + fk];
#pragma unroll
      for (int n = 0; n < 4; ++n) b[n] = *(const bfx8*)&Bs[(wn + (n << 4) + fr) * 64 + kk + fk];
#pragma unroll
      for (int m = 0; m < 4; ++m)
#pragma unroll
        for (int n = 0; n < 4; ++n)
          acc[m][n] = __builtin_amdgcn_mfma_f32_16x16x32_bf16(a[m], b[n], acc[m][n], 0, 0, 0);
    }
    __syncthreads();
  }
  const int er = (l >> 4) << 2, ec = l & 15;
#pragma unroll
  for (int m = 0; m < 4; ++m)
#pragma unroll
    for (int n = 0; n < 4; ++n)
#pragma unroll
      for (int i = 0; i < 4; ++i) {
        int gr = bm + wm + (m << 4) + er + i;
        int gc = bn + wn + (n << 4) + ec;
        float v = acc[m][n][i];
        size_t idx = (size_t)gr * ldc + gc;
        if constexpr (EP == EP_F32) {
          ((float*)Cp)[idx] = v;
        } else if constexpr (EP == EP_BF16) {
          ((unsigned short*)Cp)[idx] = f2bf(v);
        } else if constexpr (EP == EP_BIASBF) {
          ((unsigned short*)Cp)[idx] = f2bf(v + bias[gc]);
        } else if constexpr (EP == EP_GATE) {
          float rv = bf2f(((const unsigned short*)P)[idx]);
          float sg = 1.f / (1.f + __expf(-v));
          ((unsigned short*)Cp)[idx] = f2bf(rv * sg);
        } else {  // EP_RESID
          float xv = ((const float*)P)[idx];
          ((float*)Cp)[idx] = v + xv + bias[gc];
        }
      }
}

// ---------------- small prep kernels ----------------------------------------
__global__ __launch_bounds__(256)
void cast_w_kernel(const float* __restrict__ in, unsigned short* __restrict__ out, int n) {
  int e = (blockIdx.x * 256 + threadIdx.x) * 4;
  if (e >= n) return;
  float4 v = *(const float4*)&in[e];
  ushort4 u;
  u.x = f2bf(v.x); u.y = f2bf(v.y); u.z = f2bf(v.z); u.w = f2bf(v.w);
  *(ushort4*)&out[e] = u;
}

// x f32 [16384,512] -> rin bf16 left half (pitch 1024)
__global__ __launch_bounds__(256)
void cast_x_kernel(const float* __restrict__ x, unsigned short* __restrict__ rin) {
  int idx = blockIdx.x * 256 + threadIdx.x;
  int e = idx * 4;
  float4 v = *(const float4*)&x[e];
  ushort4 u;
  u.x = f2bf(v.x); u.y = f2bf(v.y); u.z = f2bf(v.z); u.w = f2bf(v.w);
  int row = e >> 9, col = e & 511;
  *(ushort4*)&rin[(size_t)row * 1024 + col] = u;
}

// per-batch transpose: xT[b][d][j] = bf16(x[b][j][d])
__global__ __launch_bounds__(256)
void transpose_kernel(const float* __restrict__ x, unsigned short* __restrict__ xT) {
  __shared__ unsigned short tile[64][65];
  const int b = blockIdx.z;
  const int j0 = blockIdx.x << 6, d0 = blockIdx.y << 6;
  const int tx = threadIdx.x & 63, ty = threadIdx.x >> 6;
  const float* xb = x + (size_t)b * 2048 * 512;
  unsigned short* xTb = xT + (size_t)b * 512 * 2048;
#pragma unroll
  for (int rep = 0; rep < 16; ++rep) {
    int jj = (rep << 2) + ty;
    tile[jj][tx] = f2bf(xb[(size_t)(j0 + jj) * 512 + d0 + tx]);
  }
  __syncthreads();
#pragma unroll
  for (int rep = 0; rep < 16; ++rep) {
    int dd = (rep << 2) + ty;
    xTb[(size_t)(d0 + dd) * 2048 + j0 + tx] = tile[tx][dd];
  }
}

// row softmax with masked diagonal, f32 in -> bf16 out in place (row pitch 4096 ushorts)
__global__ __launch_bounds__(256)
void softmax_kernel(float* __restrict__ sbase) {
  __shared__ float red[8];
  const int i = blockIdx.x;
  float* sp = sbase + (size_t)i * 2048;
  const int tid = threadIdx.x;
  const int j0 = tid << 3;
  float4 va = *(const float4*)&sp[j0];
  float4 vb = *(const float4*)&sp[j0 + 4];
  float v[8] = {va.x, va.y, va.z, va.w, vb.x, vb.y, vb.z, vb.w};
#pragma unroll
  for (int k = 0; k < 8; ++k)
    if (j0 + k == i) v[k] = -1e30f;
  float m = v[0];
#pragma unroll
  for (int k = 1; k < 8; ++k) m = fmaxf(m, v[k]);
#pragma unroll
  for (int off = 32; off > 0; off >>= 1) m = fmaxf(m, __shfl_down(m, off, 64));
  if ((tid & 63) == 0) red[tid >> 6] = m;
  __syncthreads();
  m = fmaxf(fmaxf(red[0], red[1]), fmaxf(red[2], red[3]));
  float s = 0.f;
#pragma unroll
  for (int k = 0; k < 8; ++k) {
    float e = __expf(v[k] - m);
    if (j0 + k == i) e = 0.f;
    v[k] = e;
    s += e;
  }
#pragma unroll
  for (int off = 32; off > 0; off >>= 1) s += __shfl_down(s, off, 64);
  if ((tid & 63) == 0) red[4 + (tid >> 6)] = s;
  __syncthreads();  // also guarantees every wave finished its loads (in-place safety)
  s = red[4] + red[5] + red[6] + red[7];
  float inv = 1.f / s;
  unsigned int pk[4];
#pragma unroll
  for (int k = 0; k < 4; ++k) {
    unsigned int lo = f2bf(v[2 * k] * inv);
    unsigned int hi = f2bf(v[2 * k + 1] * inv);
    pk[k] = lo | (hi << 16);
  }
  uint4 o; o.x = pk[0]; o.y = pk[1]; o.z = pk[2]; o.w = pk[3];
  *(uint4*)&((unsigned short*)sp)[j0] = o;
}

// ---------------- persistent bidirectional GRU ------------------------------
// 64 WGs: dir = wg>>5 (0 fwd, 1 bwd), slice = wg&31 owns 16 hidden units.
// Whh rows (r,z,n for those units) pre-loaded as MFMA B-fragments in registers.
// Fence-free protocol: h state + per-WG flags via relaxed agent-scope (sc1)
// atomics (MALL-coherent). NO fences -> no bulk L2 wbl2/inv per step.
__global__ __launch_bounds__(256)
void gru_kernel(const unsigned short* __restrict__ xw_f,
                const unsigned short* __restrict__ xw_b,
                const unsigned short* __restrict__ Whh_f,
                const unsigned short* __restrict__ Whh_b,
                const float* __restrict__ bhh_f,
                const float* __restrict__ bhh_b,
                unsigned short* __restrict__ hcat,
                unsigned int* __restrict__ hstate,  // [2 dir][2 phase][2048 uints]
                unsigned int* __restrict__ flags) { // [2 dir][32 wg][32 pad]
  const int wg = blockIdx.x;
  const int dir = wg >> 5;
  const int slice = wg & 31;
  const int u0 = slice << 4;
  const unsigned short* __restrict__ xwp = dir ? xw_b : xw_f;
  const unsigned short* __restrict__ Whh = dir ? Whh_b : Whh_f;
  const float* __restrict__ bhh = dir ? bhh_b : bhh_f;
  unsigned int* hbase = hstate + dir * 2 * 2048;
  unsigned int* myflags = flags + dir * 32 * 32;  // each flag on own 128B line

  __shared__ __attribute__((aligned(16))) unsigned short hbf[16 * 544];
  __shared__ float ghbuf[3 * 128];

  const int tid = threadIdx.x;
  const int w = tid >> 6, l = tid & 63;
  const int fr = l & 15, fk = (l >> 4) << 3;

  for (int i = tid; i < 16 * 544; i += 256) hbf[i] = 0;

  bfx8 wfrag[16];
  if (w < 3) {
    const int grow = (w << 9) + u0 + fr;  // gate*512 + unit
#pragma unroll
    for (int ks = 0; ks < 16; ++ks)
      wfrag[ks] = *(const bfx8*)&Whh[(size_t)grow * 512 + (ks << 5) + fk];
  }
  const int b_ = tid >> 4, uu_ = tid & 15;
  float bh0 = 0.f, bh1 = 0.f, bh2 = 0.f;
  if (tid < 128) {
    bh0 = bhh[u0 + uu_];
    bh1 = bhh[512 + u0 + uu_];
    bh2 = bhh[1024 + u0 + uu_];
  }
  __syncthreads();

  float xr = 0.f, xz = 0.f, xn = 0.f;
  if (tid < 128) {
    int ta = dir ? 2047 : 0;
    size_t rb = (size_t)(b_ * 2048 + ta) * 1536;
    xr = bf2f(xwp[rb + u0 + uu_]);
    xz = bf2f(xwp[rb + 512 + u0 + uu_]);
    xn = bf2f(xwp[rb + 1024 + u0 + uu_]);
  }

  for (int t = 0; t < 2048; ++t) {
    const int t_act = dir ? (2047 - t) : t;
    // ---- wait for all 32 producer WGs to have published h_t (t>0) ----
    if (t > 0) {
      if (l < 32) {
        const unsigned int need = (unsigned int)t;
        while (__hip_atomic_load(&myflags[l << 5], __ATOMIC_RELAXED,
                                 __HIP_MEMORY_SCOPE_AGENT) < need) {
        }
      }
      asm volatile("" ::: "memory");
    }
    // ---- load h_t from MALL into LDS (packed uints, all 256 threads) ----
    {
      const unsigned int* hr = hbase + (t & 1) * 2048;
      const int j0 = tid << 3;
#pragma unroll
      for (int q = 0; q < 8; ++q) {
        unsigned int v = __hip_atomic_load(&hr[j0 + q], __ATOMIC_RELAXED,
                                           __HIP_MEMORY_SCOPE_AGENT);
        int j = j0 + q;
        *(unsigned int*)&hbf[(j >> 8) * 544 + ((j & 255) << 1)] = v;
      }
    }
    __syncthreads();
    if (w < 3) {
      fx4 z4 = {0.f, 0.f, 0.f, 0.f};
      fx4 acc0 = z4, acc1 = z4;
#pragma unroll
      for (int ks = 0; ks < 16; ks += 2) {
        bfx8 a0 = *(const bfx8*)&hbf[fr * 544 + (ks << 5) + fk];
        bfx8 a1 = *(const bfx8*)&hbf[fr * 544 + ((ks + 1) << 5) + fk];
        acc0 = __builtin_amdgcn_mfma_f32_16x16x32_bf16(a0, wfrag[ks], acc0, 0, 0, 0);
        acc1 = __builtin_amdgcn_mfma_f32_16x16x32_bf16(a1, wfrag[ks + 1], acc1, 0, 0, 0);
      }
      if (l < 32) {
#pragma unroll
        for (int i = 0; i < 4; ++i) {
          int bb = ((l >> 4) << 2) + i;  // batch row 0..7
          ghbuf[(w << 7) + (bb << 4) + fr] = acc0[i] + acc1[i];
        }
      }
    }
    __syncthreads();
    if (tid < 128) {
      float ghr = ghbuf[tid] + bh0;
      float ghz = ghbuf[128 + tid] + bh1;
      float ghn = ghbuf[256 + tid] + bh2;
      float r = 1.f / (1.f + __expf(-(xr + ghr)));
      float z = 1.f / (1.f + __expf(-(xz + ghz)));
      float n = tanhf(xn + r * ghn);
      float hprev = bf2f(hbf[b_ * 544 + u0 + uu_]);
      float hn = (1.f - z) * n + z * hprev;
      unsigned short hnb = f2bf(hn);
      // pack pairs (uu even | uu odd) into one uint and publish via sc1 store
      unsigned int partner = (unsigned int)__shfl_down((int)hnb, 1);
      if ((tid & 1) == 0) {
        unsigned int pv = (unsigned int)hnb | (partner << 16);
        unsigned int* hw = hbase + ((t + 1) & 1) * 2048;
        __hip_atomic_store(&hw[(b_ << 8) + ((u0 + uu_) >> 1)], pv,
                           __ATOMIC_RELAXED, __HIP_MEMORY_SCOPE_AGENT);
      }
      hcat[((size_t)(b_ * 2048 + t_act) << 10) + (dir << 9) + u0 + uu_] = hnb;
    }
    if (w < 2) asm volatile("s_waitcnt vmcnt(0)" ::: "memory");  // drain h stores
    __syncthreads();  // both producer waves drained before flag
    if (tid == 0 && t + 1 < 2048)
      __hip_atomic_store(&myflags[slice << 5], (unsigned int)(t + 1),
                         __ATOMIC_RELAXED, __HIP_MEMORY_SCOPE_AGENT);
    // ---- prefetch next xw (overlaps with next step's flag poll) ----
    if (t + 1 < 2048 && tid < 128) {
      int ta = dir ? (2046 - t) : (t + 1);
      size_t rb = (size_t)(b_ * 2048 + ta) * 1536;
      xr = bf2f(xwp[rb + u0 + uu_]);
      xz = bf2f(xwp[rb + 512 + u0 + uu_]);
      xn = bf2f(xwp[rb + 1024 + u0 + uu_]);
    }
  }
}

// ---------------------------------------------------------------------------
extern "C" void kernel_launch(void* const* d_in, const int* in_sizes, int n_in,
                              void* d_out, int out_size, void* d_ws, size_t ws_size,
                              hipStream_t stream) {
  (void)in_sizes; (void)n_in; (void)out_size;
  const float* x    = (const float*)d_in[0];
  const float* W    = (const float*)d_in[1];
  const float* Wg   = (const float*)d_in[2];
  const float* Wihf = (const float*)d_in[3];
  const float* Whhf = (const float*)d_in[4];
  const float* bihf = (const float*)d_in[5];
  const float* bhhf = (const float*)d_in[6];
  const float* Wihb = (const float*)d_in[7];
  const float* Whhb = (const float*)d_in[8];
  const float* bihb = (const float*)d_in[9];
  const float* bhhb = (const float*)d_in[10];
  const float* Wp   = (const float*)d_in[11];
  const float* bp   = (const float*)d_in[12];
  float* out = (float*)d_out;

  char* base = (char*)d_ws;
  size_t off = 0;
  auto alloc = [&](size_t b) { void* r = base + off; off += (b + 255) & ~(size_t)255; return r; };
  unsigned short* xT   = (unsigned short*)alloc(8ull * 512 * 2048 * 2);
  unsigned short* xwf  = (unsigned short*)alloc(16384ull * 1536 * 2);
  unsigned short* xwb  = (unsigned short*)alloc(16384ull * 1536 * 2);
  unsigned short* rin  = (unsigned short*)alloc(16384ull * 1024 * 2);
  unsigned short* ring = (unsigned short*)alloc(16384ull * 1024 * 2);
  unsigned short* wW   = (unsigned short*)alloc(512ull * 512 * 2);
  unsigned short* wWg  = (unsigned short*)alloc(1024ull * 1024 * 2);
  unsigned short* wIf  = (unsigned short*)alloc(1536ull * 1024 * 2);
  unsigned short* wHf  = (unsigned short*)alloc(1536ull * 512 * 2);
  unsigned short* wIb  = (unsigned short*)alloc(1536ull * 1024 * 2);
  unsigned short* wHb  = (unsigned short*)alloc(1536ull * 512 * 2);
  unsigned short* wP   = (unsigned short*)alloc(512ull * 1024 * 2);
  unsigned int*   hst  = (unsigned int*)alloc(2ull * 2 * 2048 * 4);
  unsigned int*   flg  = (unsigned int*)alloc(8192);
  // overlays (lifetimes disjoint):
  float* sbuf = (float*)xwf;           // s scores, dead before xw_f written
  unsigned short* wxbf = ring;         // Wx, dead before ring written
  unsigned short* hcat = rin;          // GRU output, written after rin dead
  if (off > ws_size) return;           // fail loudly (output stays poisoned)

  hipMemsetAsync(hst, 0, 2 * 2 * 2048 * 4, stream);
  hipMemsetAsync(flg, 0, 8192, stream);

  // weight casts
  cast_w_kernel<<<256,  256, 0, stream>>>(W,    wW,  512 * 512);
  cast_w_kernel<<<1024, 256, 0, stream>>>(Wg,   wWg, 1024 * 1024);
  cast_w_kernel<<<1536, 256, 0, stream>>>(Wihf, wIf, 1536 * 1024);
  cast_w_kernel<<<768,  256, 0, stream>>>(Whhf, wHf, 1536 * 512);
  cast_w_kernel<<<1536, 256, 0, stream>>>(Wihb, wIb, 1536 * 1024);
  cast_w_kernel<<<768,  256, 0, stream>>>(Whhb, wHb, 1536 * 512);
  cast_w_kernel<<<512,  256, 0, stream>>>(Wp,   wP,  512 * 1024);

  cast_x_kernel<<<8192, 256, 0, stream>>>(x, rin);
  transpose_kernel<<<dim3(32, 8, 8), 256, 0, stream>>>(x, xT);

  // Wx = x @ W^T  (A = rin left half)
  gemm_bt<EP_BF16><<<dim3(4, 128), 256, 0, stream>>>(rin, 1024, wW, 512, wxbf, 512, 512, nullptr, nullptr);

  // attention per batch: s -> softmax -> c (into rin[:,512:])
  for (int b = 0; b < 8; ++b) {
    gemm_bt<EP_F32><<<dim3(16, 16), 256, 0, stream>>>(
        wxbf + (size_t)b * 2048 * 512, 512, rin + (size_t)b * 2048 * 1024, 1024,
        sbuf, 2048, 512, nullptr, nullptr);
    softmax_kernel<<<2048, 256, 0, stream>>>(sbuf);
    gemm_bt<EP_BF16><<<dim3(4, 16), 256, 0, stream>>>(
        (const unsigned short*)sbuf, 4096, xT + (size_t)b * 512 * 2048, 2048,
        rin + (size_t)b * 2048 * 1024 + 512, 1024, 2048, nullptr, nullptr);
  }

  // gated concat: ring = rin * sigmoid(rin @ Wg^T)
  gemm_bt<EP_GATE><<<dim3(8, 128), 256, 0, stream>>>(rin, 1024, wWg, 1024, ring, 1024, 1024, rin, nullptr);

  // GRU input gates
  gemm_bt<EP_BIASBF><<<dim3(12, 128), 256, 0, stream>>>(ring, 1024, wIf, 1024, xwf, 1536, 1024, nullptr, bihf);
  gemm_bt<EP_BIASBF><<<dim3(12, 128), 256, 0, stream>>>(ring, 1024, wIb, 1024, xwb, 1536, 1024, nullptr, bihb);

  // persistent bidirectional GRU scan (writes hcat over rin region)
  gru_kernel<<<64, 256, 0, stream>>>(xwf, xwb, wHf, wHb, bhhf, bhhb, hcat, hst, flg);

  // out = x + hcat @ Wp^T + bp
  gemm_bt<EP_RESID><<<dim3(4, 128), 256, 0, stream>>>(hcat, 1024, wP, 1024, out, 512, 1024, x, bp);
}